// Round 12
// baseline (515.927 us; speedup 1.0000x reference)
//
#include <hip/hip_runtime.h>
#include <hip/hip_bf16.h>

#define BATCH 64
#define SEQ   256
#define EMB   64
#define QKVD  64
#define KD    8192      // L*EMB
#define ND    8192      // L*QKV
#define SEQD  16384     // SEQ*EMB (per-batch x row)
#define BKP   512       // k per W-pair slot (2KB per row per visit)
#define BKH2  128       // k per A half-tile
#define NPAIR (KD / BKP)    // 16
#define NHALF (KD / BKH2)   // 64

typedef __attribute__((ext_vector_type(8))) short bf16x8;
typedef __attribute__((ext_vector_type(4))) float f32x4;

struct WArgs { const float* W[6]; const float* b[6]; };

// branchless round-to-nearest-even fp32 -> bf16 bits (inputs are finite)
__device__ __forceinline__ short f2bf(float f) {
    unsigned u = __builtin_bit_cast(unsigned, f);
    u += 0x7fffu + ((u >> 16) & 1u);
    return (short)(u >> 16);
}

// async global->LDS, 16B per lane; LDS dest = wave-uniform base + lane*16
__device__ __forceinline__ void gl16(const void* g, void* l) {
    __builtin_amdgcn_global_load_lds(
        (const __attribute__((address_space(1))) void*)g,
        (__attribute__((address_space(3))) void*)l, 16, 0, 0);
}

__device__ __forceinline__ void barrier_fenced() {
    asm volatile("" ::: "memory");
    __builtin_amdgcn_s_barrier();
    asm volatile("" ::: "memory");
}

// ---------------- kernel 1: x fp32 -> bf16 ----------------------------------
__global__ __launch_bounds__(256)
void cvt_x_kernel(const float* __restrict__ x, short* __restrict__ xb) {
    const int i = (blockIdx.x * 256 + threadIdx.x) * 4;
    float4 v = *reinterpret_cast<const float4*>(x + i);
    short4 o;
    o.x = f2bf(v.x); o.y = f2bf(v.y); o.z = f2bf(v.z); o.w = f2bf(v.w);
    *reinterpret_cast<short4*>(xb + i) = o;
}

// ---------------- kernel 2: QKV projections ---------------------------------
// C[m][n] = sum_k xs[m,k] * W[n,k] + b[n], per gi in [0,6)
// Block = 64m x 32n, 4 waves: wave (mh=wv&1, gr=wv>>1) computes 32m x 16n.
// W: per n-group ring-2 slots [16 rows][512k f32] (4 x 32KB = 128KB). Staged
//   per PAIR (512k) with TWO back-to-back 1KB issues per row -> 2KB contiguous
//   DRAM runs (the run-length lever: 256B->4.0, 512B->4.35, 1KB->4.83 TB/s).
// A: ring-2 half-tiles [64][128k] bf16 (2 x 16KB). Total LDS = 160KB exact.
// Counted-vmcnt ledger per wave (16 W-issues/pair, 4 A-issues/half):
//   waits 4,4,20,20 across the 4 halves of a pair; W(p+1) issued mid-pair
//   stays in flight across the pair boundary. Never drains except final half.
__global__ __launch_bounds__(256, 1)
void qkv_gemm_kernel(const short* __restrict__ xb, WArgs wa,
                     float* __restrict__ qkv) {
    __shared__ __attribute__((aligned(16))) float W_lds[2][2][16 * BKP]; // 128KB
    __shared__ __attribute__((aligned(16))) short A_lds[2][64 * BKH2];   // 32KB

    const int wv = threadIdx.x >> 6;
    const int ln = threadIdx.x & 63;
    const int r  = ln & 15;           // n within group / frag index
    const int kb = ln >> 4;           // k sub-block of 8 within 32
    const int gr = wv >> 1;           // n-group (0/1)
    const int mh = wv & 1;            // m-half (0/1)

    // bijective XCD swizzle: 1536 blocks = 8 * 192
    const int bid     = blockIdx.x;
    const int logical = (bid & 7) * 192 + (bid >> 3);
    const int gi      = logical >> 8;          // 0..5
    const int n0      = (logical & 255) * 32;  // n-tile origin
    const int g       = gi / 3;

    const char*  __restrict__ Wgrp =
        (const char*)(wa.W[gi] + (size_t)(n0 + gr * 16) * KD);
    const short* __restrict__ Ag = xb + g * KD;

    f32x4 acc0 = {0.f, 0.f, 0.f, 0.f};
    f32x4 acc1 = acc0;

    // W stage: wave stages 8 of its group's 16 rows, 2 adjacent 1KB issues
    // per row (2KB contiguous run). 16 issues/wave/pair.
    auto stageW = [&](int p, int slot) {
        const char* pb = Wgrp + (size_t)p * 2048;       // pair k-base (bytes)
        #pragma unroll
        for (int i = 0; i < 8; ++i) {
            const int row = mh * 8 + i;
            const char* rp = pb + (size_t)row * (KD * 4);
            char* ld = (char*)&W_lds[gr][slot][0] + row * 2048;
            #pragma unroll
            for (int j = 0; j < 2; ++j) {
                const int sc = (j * 64 + ln) ^ (row & 7);   // pre-swizzle (#21)
                gl16(rp + sc * 16, ld + j * 1024 + ln * 16);
            }
        }
    };

    // A stage: half-tile [64 rows][128k] bf16; 4 issues/wave (4 rows x 256B).
    auto stageA = [&](int h) {
        short* slot = &A_lds[h & 1][0];
        const char* hb = (const char*)Ag + (size_t)h * 256;  // h*128 shorts
        #pragma unroll
        for (int ii = 0; ii < 4; ++ii) {
            const int row = wv * 16 + ii * 4 + (ln >> 4);
            const int sc  = (ln & 15) ^ ((row & 7) << 1);    // pre-swizzle
            gl16(hb + (size_t)row * (SEQD * 2) + sc * 16,
                 (char*)slot + (wv * 4 + ii) * 1024 + ln * 16);
        }
    };

    auto compute = [&](int h) {
        const float* Wrow = &W_lds[gr][(h >> 2) & 1][0] + r * BKP;
        const char*  Ab   = (const char*)&A_lds[h & 1][0];
        const int    key  = r & 7;
        #pragma unroll
        for (int s = 0; s < 4; ++s) {
            const int lg = (h & 3) * 32 + s * 8 + kb * 2;    // chunk in row
            f32x4 w0 = *(const f32x4*)(Wrow + (((lg)     ^ key) << 2));
            f32x4 w1 = *(const f32x4*)(Wrow + (((lg + 1) ^ key) << 2));
            bf16x8 bb;
            bb[0] = f2bf(w0[0]); bb[1] = f2bf(w0[1]);
            bb[2] = f2bf(w0[2]); bb[3] = f2bf(w0[3]);
            bb[4] = f2bf(w1[0]); bb[5] = f2bf(w1[1]);
            bb[6] = f2bf(w1[2]); bb[7] = f2bf(w1[3]);
            const int ca = ((s * 4 + kb) ^ (key << 1)) << 4; // A byte chunk
            const bf16x8 a0 = *(const bf16x8*)(Ab + (mh * 32 + r)      * 256 + ca);
            const bf16x8 a1 = *(const bf16x8*)(Ab + (mh * 32 + 16 + r) * 256 + ca);
            acc0 = __builtin_amdgcn_mfma_f32_16x16x32_bf16(a0, bb, acc0, 0, 0, 0);
            acc1 = __builtin_amdgcn_mfma_f32_16x16x32_bf16(a1, bb, acc1, 0, 0, 0);
        }
    };

    // prologue ledger per wave: W(0)x16, A(0)x4, A(1)x4
    stageW(0, 0);
    stageA(0);
    stageA(1);
    __builtin_amdgcn_sched_barrier(0);

    for (int p = 0; p < NPAIR; ++p) {
        const int h = 4 * p;
        const bool morew = (p + 1 < NPAIR);

        // half h+0: newer-than-A(h) = A(h+1) -> vmcnt(4)
        asm volatile("s_waitcnt vmcnt(4)" ::: "memory");
        barrier_fenced();
        compute(h);
        barrier_fenced();
        stageA(h + 2);
        __builtin_amdgcn_sched_barrier(0);

        // half h+1: newer = A(h+2) -> vmcnt(4)
        asm volatile("s_waitcnt vmcnt(4)" ::: "memory");
        barrier_fenced();
        compute(h + 1);
        barrier_fenced();
        stageA(h + 3);
        if (morew) stageW(p + 1, (p + 1) & 1);
        __builtin_amdgcn_sched_barrier(0);

        // half h+2: newer = A(h+3) [+ W(p+1)] -> vmcnt(20|4)
        if (morew) { asm volatile("s_waitcnt vmcnt(20)" ::: "memory"); }
        else       { asm volatile("s_waitcnt vmcnt(4)"  ::: "memory"); }
        barrier_fenced();
        compute(h + 2);
        barrier_fenced();
        if (h + 4 < NHALF) stageA(h + 4);
        __builtin_amdgcn_sched_barrier(0);

        // half h+3: newer = W(p+1) + A(h+4) -> vmcnt(20), last pair -> 0
        if (morew) { asm volatile("s_waitcnt vmcnt(20)" ::: "memory"); }
        else       { asm volatile("s_waitcnt vmcnt(0)"  ::: "memory"); }
        barrier_fenced();
        compute(h + 3);
        barrier_fenced();
        if (h + 5 < NHALF) stageA(h + 5);
        __builtin_amdgcn_sched_barrier(0);
    }

    // D layout (m89): col = lane&15, row = (lane>>4)*4 + reg
    const int nbr = n0 + gr * 16 + r;
    const float bias = wa.b[gi][nbr];
    float* orow = qkv + (size_t)gi * (BATCH * ND) + nbr;
    #pragma unroll
    for (int reg = 0; reg < 4; ++reg) {
        const int m = mh * 32 + kb * 4 + reg;
        orow[(size_t)(m)      * ND] = acc0[reg] + bias;
        orow[(size_t)(m + 16) * ND] = acc1[reg] + bias;
    }
}

// ---------------- kernel 3: attention per (batch, group) -------------------
// scores[i][j] = Q[i,:]·K[j,:]; softmax over i (query axis); Z = attn·V; ×0.125
__global__ __launch_bounds__(256)
void attn_kernel(const float* __restrict__ qkv, float* __restrict__ out) {
    __shared__ float Ql[128 * 65];   // Q, then reused for V
    __shared__ float Kl[128 * 65];
    __shared__ float Sc[128 * 129];
    __shared__ float Pm[256];
    __shared__ float Ps[256];
    __shared__ float Rden[128];

    const int b = blockIdx.x;
    const int g = blockIdx.y;
    const int t = threadIdx.x;

    const float* __restrict__ Qg = qkv + ((size_t)(3 * g + 0) * BATCH + b) * ND;
    const float* __restrict__ Kg = qkv + ((size_t)(3 * g + 1) * BATCH + b) * ND;
    const float* __restrict__ Vg = qkv + ((size_t)(3 * g + 2) * BATCH + b) * ND;

    for (int e = t; e < 8192; e += 256) {
        const int i = e >> 6, k = e & 63;
        Ql[i * 65 + k] = Qg[e];
        Kl[i * 65 + k] = Kg[e];
    }
    __syncthreads();

    // scores: 8x8 register tile per thread
    {
        const int i0 = (t >> 4) * 8;
        const int j0 = (t & 15) * 8;
        float s[8][8];
        #pragma unroll
        for (int rr = 0; rr < 8; ++rr)
            #pragma unroll
            for (int cc = 0; cc < 8; ++cc) s[rr][cc] = 0.f;
        for (int k = 0; k < 64; ++k) {
            float qv[8], kv[8];
            #pragma unroll
            for (int rr = 0; rr < 8; ++rr) qv[rr] = Ql[(i0 + rr) * 65 + k];
            #pragma unroll
            for (int cc = 0; cc < 8; ++cc) kv[cc] = Kl[(j0 + cc) * 65 + k];
            #pragma unroll
            for (int rr = 0; rr < 8; ++rr)
                #pragma unroll
                for (int cc = 0; cc < 8; ++cc)
                    s[rr][cc] = fmaf(qv[rr], kv[cc], s[rr][cc]);
        }
        #pragma unroll
        for (int rr = 0; rr < 8; ++rr)
            #pragma unroll
            for (int cc = 0; cc < 8; ++cc)
                Sc[(i0 + rr) * 129 + (j0 + cc)] = s[rr][cc];
    }
    __syncthreads();

    // V fill (Q dead) + per-column partial max; column j, half h
    const int j = t & 127, h = t >> 7;
    {
        for (int e = t; e < 8192; e += 256) {
            const int i = e >> 6, k = e & 63;
            Ql[i * 65 + k] = Vg[e];
        }
        float m = -3.0e38f;
        for (int i = h * 64; i < h * 64 + 64; ++i)
            m = fmaxf(m, Sc[i * 129 + j]);
        Pm[h * 128 + j] = m;
    }
    __syncthreads();
    {
        const float m = fmaxf(Pm[j], Pm[128 + j]);
        float sum = 0.f;
        for (int i = h * 64; i < h * 64 + 64; ++i) {
            const float e = __expf(Sc[i * 129 + j] - m);
            Sc[i * 129 + j] = e;
            sum += e;
        }
        Ps[h * 128 + j] = sum;
    }
    __syncthreads();
    if (t < 128) Rden[t] = 1.0f / (Ps[t] + Ps[128 + t]);
    __syncthreads();

    // PV: 8 rows x 4 cols per thread
    {
        const int i0 = (t >> 4) * 8;
        const int k0 = (t & 15) * 4;
        float z[8][4];
        #pragma unroll
        for (int rr = 0; rr < 8; ++rr)
            #pragma unroll
            for (int cc = 0; cc < 4; ++cc) z[rr][cc] = 0.f;
        for (int jj = 0; jj < 128; ++jj) {
            const float rd = Rden[jj];
            float av[8], vv[4];
            #pragma unroll
            for (int rr = 0; rr < 8; ++rr) av[rr] = Sc[(i0 + rr) * 129 + jj] * rd;
            #pragma unroll
            for (int cc = 0; cc < 4; ++cc) vv[cc] = Ql[jj * 65 + k0 + cc];
            #pragma unroll
            for (int rr = 0; rr < 8; ++rr)
                #pragma unroll
                for (int cc = 0; cc < 4; ++cc)
                    z[rr][cc] = fmaf(av[rr], vv[cc], z[rr][cc]);
        }
        float* op = out + (size_t)b * (SEQ * QKVD) + (size_t)(g * 128) * QKVD + k0;
        #pragma unroll
        for (int rr = 0; rr < 8; ++rr) {
            float4 o;
            o.x = z[rr][0] * 0.125f; o.y = z[rr][1] * 0.125f;
            o.z = z[rr][2] * 0.125f; o.w = z[rr][3] * 0.125f;
            *reinterpret_cast<float4*>(op + (size_t)(i0 + rr) * QKVD) = o;
        }
    }
}

// ---------------- launcher --------------------------------------------------
extern "C" void kernel_launch(void* const* d_in, const int* in_sizes, int n_in,
                              void* d_out, int out_size, void* d_ws, size_t ws_size,
                              hipStream_t stream) {
    const float* x = (const float*)d_in[0];
    WArgs wa;
    for (int g = 0; g < 2; ++g)
        for (int q = 0; q < 3; ++q) {
            wa.W[g * 3 + q] = (const float*)d_in[1 + g * 6 + q * 2];
            wa.b[g * 3 + q] = (const float*)d_in[2 + g * 6 + q * 2];
        }

    short* xb  = (short*)d_ws;                                      // 2 MiB
    float* qkv = (float*)((char*)d_ws + (size_t)4 * 1024 * 1024);   // 12.6 MiB

    cvt_x_kernel<<<dim3(1024), dim3(256), 0, stream>>>(x, xb);
    qkv_gemm_kernel<<<dim3(1536), dim3(256), 0, stream>>>(xb, wa, qkv);
    attn_kernel<<<dim3(BATCH, 2), dim3(256), 0, stream>>>(qkv, (float*)d_out);
}